// Round 11
// baseline (535.832 us; speedup 1.0000x reference)
//
#include <hip/hip_runtime.h>
#include <stdint.h>

typedef unsigned short u16;
typedef __attribute__((ext_vector_type(8))) __bf16 bf16x8;
typedef __attribute__((ext_vector_type(4))) float f32x4;

// ---------- helpers ----------
__device__ __forceinline__ u16 f2bf(float f) {  // RNE fp32 -> bf16
  unsigned int u = __builtin_bit_cast(unsigned int, f);
  u = (u + 0x7FFFu + ((u >> 16) & 1u)) >> 16;
  return (u16)u;
}
__device__ __forceinline__ u16 tern2bf(int s) {
  return s == 0 ? (u16)0 : (s > 0 ? (u16)0x3F80 : (u16)0xBF80);
}

#define GLOAD_LDS16(g, l)                                                          \
  __builtin_amdgcn_global_load_lds((__attribute__((address_space(1))) void*)(g),   \
                                   (__attribute__((address_space(3))) void*)(l),   \
                                   16, 0, 0)

// ---------- problem sizes ----------
#define M_TOK 8192
#define N_OUT 4096
#define K_IN  4096
#define RANK  32

// ---------- ws layout (bytes) ----------
#define WS_XB    0ull
#define WS_WB    67108864ull
#define WS_BB    100663296ull
#define WS_A32   100925440ull
#define WS_T32   101187584ull
#define WS_TPART 101711872ull
#define WS_FLAG  110100480ull

// ---------- prep: detect W dtype + convert loraB -> bb + loraA/scale -> a32 ----------
__global__ __launch_bounds__(256) void k_prep(const int* __restrict__ wq,
                                              const float* __restrict__ loraA,
                                              const float* __restrict__ loraB,
                                              const float* __restrict__ scale,
                                              u16* __restrict__ bb,
                                              u16* __restrict__ a32,
                                              int* __restrict__ flag) {
  if (blockIdx.x == 0 && threadIdx.x < 64) {
    int v = wq[threadIdx.x];
    bool ok = (v >= -1 && v <= 1);
    unsigned long long m = __ballot(ok);
    if (threadIdx.x == 0) *flag = (m == ~0ull) ? 1 : 0;
  }
  int idx = blockIdx.x * 256 + threadIdx.x;
  if (blockIdx.x < 512) {  // bb: 32*4096 = 131072 elems
    bb[idx] = f2bf(loraB[idx]);
  } else {  // a32: 4096*32 = 131072 elems
    int j = idx - 131072;
    int o = j >> 5;
    a32[j] = f2bf(loraA[j] / scale[o]);
  }
}

__global__ void k_convert_w(const void* __restrict__ wq, const int* __restrict__ flag,
                            ushort4* __restrict__ wb, int n4) {
  int is32 = *flag;
  int stride = gridDim.x * blockDim.x;
  for (int i = blockIdx.x * blockDim.x + threadIdx.x; i < n4; i += stride) {
    int s0, s1, s2, s3;
    if (is32) {
      int4 c = ((const int4*)wq)[i];
      s0 = c.x; s1 = c.y; s2 = c.z; s3 = c.w;
    } else {
      char4 c = ((const char4*)wq)[i];
      s0 = c.x; s1 = c.y; s2 = c.z; s3 = c.w;
    }
    ushort4 o;
    o.x = tern2bf(s0); o.y = tern2bf(s1); o.z = tern2bf(s2); o.w = tern2bf(s3);
    wb[i] = o;
  }
}

// ---------- fused: x f32 -> xb bf16, AND T-partials = x @ B^T ----------
// 2048 blocks = 256 token-groups(32 tok) x 8 k-slices(512).
// Wave wv owns tokens tg*32 + wv*8 + {0..7}, processed 2 at a time so each
// B-row ds_read_b128 is shared by two tokens. Per token: per-lane 8-elem f32
// dot-partials for all 32 ranks, 6-step shfl_xor butterfly, lane 0 writes
// tpart[ks][t][0..31]. Coverage: t = tg*32+wv*8+it*2+{0,1} spans [0,8192).
__global__ __launch_bounds__(256) void k_fused_xT(const float* __restrict__ x,
                                                  const u16* __restrict__ bb,
                                                  uint4* __restrict__ xb,
                                                  float* __restrict__ tpart) {
  __shared__ u16 Bs[32 * 512];  // 32KB
  const int b = blockIdx.x;
  const int ks = b & 7;
  const int tg = b >> 3;  // 0..255
  const int tid = threadIdx.x, l = tid & 63, wv = tid >> 6;

  // load B slice [32][512]
#pragma unroll
  for (int j = 0; j < 8; ++j) {
    int i = j * 256 + tid;
    int r = i >> 6, c = i & 63;
    *(uint4*)&Bs[r * 512 + c * 8] =
        *(const uint4*)&bb[(size_t)r * K_IN + ks * 512 + c * 8];
  }
  __syncthreads();

  const int tbase = tg * 32 + wv * 8;
#pragma unroll 1
  for (int it = 0; it < 4; ++it) {
    const int t = tbase + it * 2;
    const float* xpA = x + (size_t)t * K_IN + ks * 512 + l * 8;
    const float* xpB = xpA + K_IN;
    float4 va0 = *(const float4*)xpA;
    float4 va1 = *(const float4*)(xpA + 4);
    float4 vb0 = *(const float4*)xpB;
    float4 vb1 = *(const float4*)(xpB + 4);
    u16 oA[8], oB[8];
    oA[0] = f2bf(va0.x); oA[1] = f2bf(va0.y); oA[2] = f2bf(va0.z); oA[3] = f2bf(va0.w);
    oA[4] = f2bf(va1.x); oA[5] = f2bf(va1.y); oA[6] = f2bf(va1.z); oA[7] = f2bf(va1.w);
    oB[0] = f2bf(vb0.x); oB[1] = f2bf(vb0.y); oB[2] = f2bf(vb0.z); oB[3] = f2bf(vb0.w);
    oB[4] = f2bf(vb1.x); oB[5] = f2bf(vb1.y); oB[6] = f2bf(vb1.z); oB[7] = f2bf(vb1.w);
    uint4 pkA, pkB;
    pkA.x = (unsigned)oA[0] | ((unsigned)oA[1] << 16);
    pkA.y = (unsigned)oA[2] | ((unsigned)oA[3] << 16);
    pkA.z = (unsigned)oA[4] | ((unsigned)oA[5] << 16);
    pkA.w = (unsigned)oA[6] | ((unsigned)oA[7] << 16);
    pkB.x = (unsigned)oB[0] | ((unsigned)oB[1] << 16);
    pkB.y = (unsigned)oB[2] | ((unsigned)oB[3] << 16);
    pkB.z = (unsigned)oB[4] | ((unsigned)oB[5] << 16);
    pkB.w = (unsigned)oB[6] | ((unsigned)oB[7] << 16);
    size_t xoff = ((size_t)t * K_IN + ks * 512 + l * 8) / 8;
    xb[xoff] = pkA;
    xb[xoff + K_IN / 8] = pkB;

    float xfA[8], xfB[8];
#pragma unroll
    for (int j = 0; j < 8; ++j) {
      xfA[j] = __builtin_bit_cast(float, ((unsigned)oA[j]) << 16);
      xfB[j] = __builtin_bit_cast(float, ((unsigned)oB[j]) << 16);
    }

    float accA[32], accB[32];
#pragma unroll
    for (int r = 0; r < 32; ++r) { accA[r] = 0.f; accB[r] = 0.f; }
#pragma unroll
    for (int r = 0; r < 32; ++r) {
      const uint4 braw = *(const uint4*)&Bs[r * 512 + l * 8];
      const unsigned q[4] = {braw.x, braw.y, braw.z, braw.w};
#pragma unroll
      for (int p = 0; p < 4; ++p) {
        float e0 = __builtin_bit_cast(float, q[p] << 16);
        float e1 = __builtin_bit_cast(float, q[p] & 0xFFFF0000u);
        accA[r] += xfA[2 * p] * e0 + xfA[2 * p + 1] * e1;
        accB[r] += xfB[2 * p] * e0 + xfB[2 * p + 1] * e1;
      }
    }
#pragma unroll
    for (int m = 1; m < 64; m <<= 1) {
#pragma unroll
      for (int r = 0; r < 32; ++r) {
        accA[r] += __shfl_xor(accA[r], m, 64);
        accB[r] += __shfl_xor(accB[r], m, 64);
      }
    }
    if (l == 0) {
      float* dA = tpart + ((size_t)ks * M_TOK + t) * RANK;
#pragma unroll
      for (int r = 0; r < 32; ++r) { dA[r] = accA[r]; dA[RANK + r] = accB[r]; }
    }
  }
}

__global__ void k_reduce_T(const float* __restrict__ tpart, u16* __restrict__ t32) {
  int idx = blockIdx.x * blockDim.x + threadIdx.x;
  if (idx >= M_TOK * RANK) return;
  int t = idx >> 5, r = idx & 31;
  float v = 0.f;
#pragma unroll
  for (int s = 0; s < 8; ++s) v += tpart[((size_t)s * M_TOK + t) * RANK + r];
  t32[idx] = f2bf(v);
}

// ---------- main GEMM: 256x256, BK=32, ring-4 LDS, FULL-tile frag read-ahead ----------
// EXACT R7 kernel (measured 238us, MfmaUtil 50.5%, 0 bank conflicts).
__global__ __launch_bounds__(512, 2) void k_gemm8(const u16* __restrict__ xb,
                                                  const u16* __restrict__ wb,
                                                  const u16* __restrict__ t32,
                                                  const u16* __restrict__ a32,
                                                  const float* __restrict__ scale,
                                                  const float* __restrict__ bias,
                                                  float* __restrict__ out) {
  __shared__ u16 As[4][8192];  // 4 slots x 16KB
  __shared__ u16 Bs[4][8192];
  const int tid = threadIdx.x;
  const int l = tid & 63, w = tid >> 6;
  const int wm = w >> 2, wn = w & 3;
  const int bid = blockIdx.x;
  const int swz = (bid & 7) * 64 + (bid >> 3);
  const int m0 = (swz >> 4) * 256, n0 = (swz & 15) * 256;

  const int srow0 = (w * 2 + 0) * 16 + (l >> 2);
  const int srow1 = (w * 2 + 1) * 16 + (l >> 2);
  const int scx = ((l & 3) ^ ((l >> 3) & 3)) * 8;
  const int ldst0 = (w * 2 + 0) * 512 + l * 8;
  const int ldst1 = (w * 2 + 1) * 512 + l * 8;
  const int r15 = l & 15;
  const int cxr = (((l >> 4) ^ ((r15 >> 1) & 3)) * 8);

  f32x4 acc[8][4] = {};

  u16* AsF = &As[0][0];
  u16* BsF = &Bs[0][0];
  const u16* axs0 = xb + (size_t)(m0 + srow0) * K_IN + scx;
  const u16* axs1 = xb + (size_t)(m0 + srow1) * K_IN + scx;
  const u16* bxs0 = wb + (size_t)(n0 + srow0) * K_IN + scx;
  const u16* bxs1 = wb + (size_t)(n0 + srow1) * K_IN + scx;

  // prologue: stage tiles 0,1,2
#pragma unroll
  for (int ts = 0; ts < 3; ++ts) {
    GLOAD_LDS16(axs0 + ts * 32, AsF + ts * 8192 + ldst0);
    GLOAD_LDS16(axs1 + ts * 32, AsF + ts * 8192 + ldst1);
    GLOAD_LDS16(bxs0 + ts * 32, BsF + ts * 8192 + ldst0);
    GLOAD_LDS16(bxs1 + ts * 32, BsF + ts * 8192 + ldst1);
  }
  asm volatile("s_waitcnt vmcnt(4)" ::: "memory");  // tiles 0,1 landed (this wave)
  asm volatile("s_barrier" ::: "memory");           // => landed cross-wave

  const int abase = (wm * 128 + r15) * 32 + cxr;
  const int bbase = (wn * 64 + r15) * 32 + cxr;

  // running stage pointers -> tile 3
  const u16* ap0 = axs0 + 96;
  const u16* ap1 = axs1 + 96;
  const u16* bp0 = bxs0 + 96;
  const u16* bp1 = bxs1 + 96;

  bf16x8 fa0[4], fa1[4], fb[4];  // single frag set, rewritten each tile

#define SA(DST)                                                                     \
  { GLOAD_LDS16(ap0, AsF + (DST) * 8192 + ldst0);                                   \
    GLOAD_LDS16(ap1, AsF + (DST) * 8192 + ldst1);                                   \
    ap0 += 32; ap1 += 32; }
#define SB(DST)                                                                     \
  { GLOAD_LDS16(bp0, BsF + (DST) * 8192 + ldst0);                                   \
    GLOAD_LDS16(bp1, BsF + (DST) * 8192 + ldst1);                                   \
    bp0 += 32; bp1 += 32; }
#define W4  asm volatile("s_waitcnt vmcnt(4)" ::: "memory");
#define W0  asm volatile("s_waitcnt vmcnt(0)" ::: "memory");
#define BARR asm volatile("s_barrier" ::: "memory");
#define READN(NS)                                                                   \
  { const u16* An = AsF + (NS) * 8192;                                              \
    const u16* Bn = BsF + (NS) * 8192;                                              \
    _Pragma("unroll") for (int mi = 0; mi < 4; ++mi)                                \
        fa0[mi] = *(const bf16x8*)&An[abase + mi * 512];                            \
    _Pragma("unroll") for (int mi = 0; mi < 4; ++mi)                                \
        fa1[mi] = *(const bf16x8*)&An[abase + 2048 + mi * 512];                     \
    _Pragma("unroll") for (int nj = 0; nj < 4; ++nj)                                \
        fb[nj] = *(const bf16x8*)&Bn[bbase + nj * 512]; }

#define TILE(STAGE, WAIT, RD, BAR)                                                  \
  {                                                                                 \
    STAGE                                                                           \
    __builtin_amdgcn_s_setprio(1);                                                  \
    _Pragma("unroll") for (int mi = 0; mi < 4; ++mi)                                \
    _Pragma("unroll") for (int nj = 0; nj < 4; ++nj)                                \
        acc[mi][nj] =                                                               \
            __builtin_amdgcn_mfma_f32_16x16x32_bf16(fa0[mi], fb[nj], acc[mi][nj], 0, 0, 0); \
    _Pragma("unroll") for (int mi = 0; mi < 4; ++mi)                                \
    _Pragma("unroll") for (int nj = 0; nj < 4; ++nj)                                \
        acc[4 + mi][nj] =                                                           \
            __builtin_amdgcn_mfma_f32_16x16x32_bf16(fa1[mi], fb[nj], acc[4 + mi][nj], 0, 0, 0); \
    __builtin_amdgcn_s_setprio(0);                                                  \
    WAIT                                                                            \
    RD                                                                              \
    BAR                                                                             \
  }

  READN(0)  // tile 0 frags (post-prologue-barrier: globally landed)

  // main loop: tiles 0..123, staging 3..127
#pragma unroll 1
  for (int t = 0; t < 124; t += 4) {
    TILE(SA(3) SB(3), W4, READN(1), BARR)
    TILE(SA(0) SB(0), W4, READN(2), BARR)
    TILE(SA(1) SB(1), W4, READN(3), BARR)
    TILE(SA(2) SB(2), W4, READN(0), BARR)
  }
  // t=124: stage tile 127 -> slot 3
  TILE(SA(3) SB(3), W4, READN(1), BARR)
  // t=125: stage LoRA tile (128) -> slot 0
  {
    const u16* la0 = t32 + (size_t)(m0 + srow0) * RANK + scx;
    const u16* la1 = t32 + (size_t)(m0 + srow1) * RANK + scx;
    const u16* lb0 = a32 + (size_t)(n0 + srow0) * RANK + scx;
    const u16* lb1 = a32 + (size_t)(n0 + srow1) * RANK + scx;
    TILE({ GLOAD_LDS16(la0, AsF + 0 * 8192 + ldst0); GLOAD_LDS16(la1, AsF + 0 * 8192 + ldst1);
           GLOAD_LDS16(lb0, BsF + 0 * 8192 + ldst0); GLOAD_LDS16(lb1, BsF + 0 * 8192 + ldst1); },
         W4, READN(2), BARR)
  }
  // t=126: full drain so LoRA slot is globally landed after this barrier
  TILE(, W0, READN(3), BARR)
  // t=127: nothing outstanding; pre-read LoRA frags (slot 0)
  TILE(, , READN(0), BARR)
  // t=128: LoRA tile, frags preloaded
  TILE(, , , )

  // epilogue: out = acc*scale[col] + bias[col]
#pragma unroll
  for (int nj = 0; nj < 4; ++nj) {
    int col = n0 + wn * 64 + nj * 16 + r15;
    float s = scale[col], bv = bias[col];
#pragma unroll
    for (int fi = 0; fi < 8; ++fi) {
      int row = m0 + wm * 128 + (fi >> 2) * 64 + (fi & 3) * 16 + (l >> 4) * 4;
#pragma unroll
      for (int r = 0; r < 4; ++r)
        out[(size_t)(row + r) * N_OUT + col] = acc[fi][nj][r] * s + bv;
    }
  }
}

// ---------- launch ----------
extern "C" void kernel_launch(void* const* d_in, const int* in_sizes, int n_in,
                              void* d_out, int out_size, void* d_ws, size_t ws_size,
                              hipStream_t stream) {
  const float* x     = (const float*)d_in[0];
  const void*  wq    = d_in[1];
  const float* scale = (const float*)d_in[2];
  const float* loraA = (const float*)d_in[3];
  const float* loraB = (const float*)d_in[4];
  const float* bias  = (const float*)d_in[5];
  float* out = (float*)d_out;

  char* ws = (char*)d_ws;
  u16*   xb    = (u16*)(ws + WS_XB);
  u16*   wbuf  = (u16*)(ws + WS_WB);
  u16*   bb    = (u16*)(ws + WS_BB);
  u16*   a32   = (u16*)(ws + WS_A32);
  u16*   t32   = (u16*)(ws + WS_T32);
  float* tpart = (float*)(ws + WS_TPART);
  int*   flag  = (int*)(ws + WS_FLAG);

  k_prep<<<1024, 256, 0, stream>>>((const int*)wq, loraA, loraB, scale, bb, a32, flag);
  k_convert_w<<<2048, 256, 0, stream>>>(wq, flag, (ushort4*)wbuf, N_OUT * K_IN / 4);
  k_fused_xT<<<2048, 256, 0, stream>>>(x, bb, (uint4*)xb, tpart);
  k_reduce_T<<<1024, 256, 0, stream>>>(tpart, t32);
  k_gemm8<<<512, 512, 0, stream>>>(xb, wbuf, t32, a32, scale, bias, out);

  (void)in_sizes; (void)n_in; (void)out_size; (void)ws_size;
}

// Round 12
// 320.158 us; speedup vs baseline: 1.6736x; 1.6736x over previous
//
#include <hip/hip_runtime.h>
#include <stdint.h>

typedef unsigned short u16;
typedef __attribute__((ext_vector_type(8))) __bf16 bf16x8;
typedef __attribute__((ext_vector_type(4))) float f32x4;

// ---------- helpers ----------
__device__ __forceinline__ u16 f2bf(float f) {  // RNE fp32 -> bf16
  unsigned int u = __builtin_bit_cast(unsigned int, f);
  u = (u + 0x7FFFu + ((u >> 16) & 1u)) >> 16;
  return (u16)u;
}
__device__ __forceinline__ u16 tern2bf(int s) {
  return s == 0 ? (u16)0 : (s > 0 ? (u16)0x3F80 : (u16)0xBF80);
}

#define GLOAD_LDS16(g, l)                                                          \
  __builtin_amdgcn_global_load_lds((__attribute__((address_space(1))) void*)(g),   \
                                   (__attribute__((address_space(3))) void*)(l),   \
                                   16, 0, 0)

// ---------- problem sizes ----------
#define M_TOK 8192
#define N_OUT 4096
#define K_IN  4096
#define RANK  32

// ---------- ws layout (bytes) ----------
#define WS_XB    0ull
#define WS_WB    67108864ull
#define WS_BB    100663296ull
#define WS_A32   100925440ull
#define WS_T32   101187584ull
#define WS_TPART 101711872ull
#define WS_FLAG  110100480ull

// ---------- prep: detect W dtype + convert loraB -> bb + loraA/scale -> a32 ----------
__global__ __launch_bounds__(256) void k_prep(const int* __restrict__ wq,
                                              const float* __restrict__ loraA,
                                              const float* __restrict__ loraB,
                                              const float* __restrict__ scale,
                                              u16* __restrict__ bb,
                                              u16* __restrict__ a32,
                                              int* __restrict__ flag) {
  if (blockIdx.x == 0 && threadIdx.x < 64) {
    int v = wq[threadIdx.x];
    bool ok = (v >= -1 && v <= 1);
    unsigned long long m = __ballot(ok);
    if (threadIdx.x == 0) *flag = (m == ~0ull) ? 1 : 0;
  }
  int idx = blockIdx.x * 256 + threadIdx.x;
  if (blockIdx.x < 512) {  // bb: 32*4096 = 131072 elems
    bb[idx] = f2bf(loraB[idx]);
  } else {  // a32: 4096*32 = 131072 elems
    int j = idx - 131072;
    int o = j >> 5;
    a32[j] = f2bf(loraA[j] / scale[o]);
  }
}

__global__ void k_convert_x(const float4* __restrict__ x, ushort4* __restrict__ xb, int n4) {
  int stride = gridDim.x * blockDim.x;
  for (int i = blockIdx.x * blockDim.x + threadIdx.x; i < n4; i += stride) {
    float4 v = x[i];
    ushort4 o;
    o.x = f2bf(v.x); o.y = f2bf(v.y); o.z = f2bf(v.z); o.w = f2bf(v.w);
    xb[i] = o;
  }
}

__global__ void k_convert_w(const void* __restrict__ wq, const int* __restrict__ flag,
                            ushort4* __restrict__ wb, int n4) {
  int is32 = *flag;
  int stride = gridDim.x * blockDim.x;
  for (int i = blockIdx.x * blockDim.x + threadIdx.x; i < n4; i += stride) {
    int s0, s1, s2, s3;
    if (is32) {
      int4 c = ((const int4*)wq)[i];
      s0 = c.x; s1 = c.y; s2 = c.z; s3 = c.w;
    } else {
      char4 c = ((const char4*)wq)[i];
      s0 = c.x; s1 = c.y; s2 = c.z; s3 = c.w;
    }
    ushort4 o;
    o.x = tern2bf(s0); o.y = tern2bf(s1); o.z = tern2bf(s2); o.w = tern2bf(s3);
    wb[i] = o;
  }
}

// ---------- T = x @ B^T (MFMA, partials over 8 K-slices) ----------
__global__ __launch_bounds__(256) void k_lora_T(const u16* __restrict__ xb,
                                                const u16* __restrict__ bb,
                                                float* __restrict__ tpart) {
  __shared__ u16 As[256 * 32];
  __shared__ u16 Bs[32 * 32];
  int mt = blockIdx.x >> 3;
  int ks = blockIdx.x & 7;
  int tid = threadIdx.x, lane = tid & 63, wave = tid >> 6;
  int m0 = mt * 256;
  int kbase0 = ks * 512;
  f32x4 acc[4][2] = {};
  for (int step = 0; step < 16; ++step) {
    int kb = kbase0 + step * 32;
    __syncthreads();
#pragma unroll
    for (int i = 0; i < 4; ++i) {
      const u16* src = xb + (size_t)(m0 + i * 64 + (tid >> 2)) * K_IN + kb + (tid & 3) * 8;
      GLOAD_LDS16(src, &As[i * 2048 + tid * 8]);
    }
    if (tid < 128) {
      const u16* src = bb + (size_t)(tid >> 2) * K_IN + kb + (tid & 3) * 8;
      GLOAD_LDS16(src, &Bs[tid * 8]);
    }
    __syncthreads();
    bf16x8 b[2];
#pragma unroll
    for (int ni = 0; ni < 2; ++ni)
      b[ni] = *(const bf16x8*)&Bs[(ni * 16 + (lane & 15)) * 32 + (lane >> 4) * 8];
#pragma unroll
    for (int mi = 0; mi < 4; ++mi) {
      bf16x8 a = *(const bf16x8*)&As[(wave * 64 + mi * 16 + (lane & 15)) * 32 + (lane >> 4) * 8];
      acc[mi][0] = __builtin_amdgcn_mfma_f32_16x16x32_bf16(a, b[0], acc[mi][0], 0, 0, 0);
      acc[mi][1] = __builtin_amdgcn_mfma_f32_16x16x32_bf16(a, b[1], acc[mi][1], 0, 0, 0);
    }
  }
#pragma unroll
  for (int mi = 0; mi < 4; ++mi)
#pragma unroll
    for (int ni = 0; ni < 2; ++ni)
#pragma unroll
      for (int r = 0; r < 4; ++r) {
        int row = m0 + wave * 64 + mi * 16 + (lane >> 4) * 4 + r;
        int col = ni * 16 + (lane & 15);
        tpart[((size_t)ks * M_TOK + row) * RANK + col] = acc[mi][ni][r];
      }
}

__global__ void k_reduce_T(const float* __restrict__ tpart, u16* __restrict__ t32) {
  int idx = blockIdx.x * blockDim.x + threadIdx.x;
  if (idx >= M_TOK * RANK) return;
  int t = idx >> 5, r = idx & 31;
  float v = 0.f;
#pragma unroll
  for (int s = 0; s < 8; ++s) v += tpart[((size_t)s * M_TOK + t) * RANK + r];
  t32[idx] = f2bf(v);
}

// ---------- main GEMM: 256x256, BK=32, ring-4 LDS, 16 waves (4Mx4N) ----------
// R7 skeleton (0-conflict swizzle, counted vmcnt, 1 barrier/tile, full-tile
// register read-ahead) at DOUBLE the wave count: 1024 threads = 16 waves
// (4 waves/SIMD) so wave de-phasing overlaps one wave's ds_reads with
// another's MFMA burst (m114 co-scheduling). Per wave: 64x64 out =
// acc[4][4] f32x4 (64 VGPR), 8 frag reads + 16-MFMA burst per K32-tile.
// Staging: 1024 threads x 16B = whole 16KB slot per gload issue (1 per
// operand per tile). Waits: prologue W4 (tile0 landed of 6 outstanding);
// steady W2 (leaves only t+3 -> t+2 landed, same invariant as R7);
// tail W2, W2, W0, none, none.
__global__ __launch_bounds__(1024, 4) void k_gemm8(const u16* __restrict__ xb,
                                                   const u16* __restrict__ wb,
                                                   const u16* __restrict__ t32,
                                                   const u16* __restrict__ a32,
                                                   const float* __restrict__ scale,
                                                   const float* __restrict__ bias,
                                                   float* __restrict__ out) {
  __shared__ u16 As[4][8192];  // 4 slots x 16KB
  __shared__ u16 Bs[4][8192];
  const int tid = threadIdx.x;
  const int l = tid & 63, w = tid >> 6;     // 16 waves
  const int wm = w >> 2, wn = w & 3;        // 4M x 4N
  const int bid = blockIdx.x;
  const int swz = (bid & 7) * 64 + (bid >> 3);
  const int m0 = (swz >> 4) * 256, n0 = (swz & 15) * 256;

  // staging map: 1024 threads cover one 16KB slot (256 rows x 32 cols bf16)
  const int srow = tid >> 2;                       // 0..255
  const int scx = ((tid & 3) ^ ((tid >> 3) & 3)) * 8;  // pre-swizzled source chunk
  const int ldst = tid * 8;                        // linear LDS dest (u16 idx)
  // frag-read map (same verified 0-conflict family as R7)
  const int r15 = l & 15;
  const int cxr = (((l >> 4) ^ ((r15 >> 1) & 3)) * 8);

  f32x4 acc[4][4] = {};

  u16* AsF = &As[0][0];
  u16* BsF = &Bs[0][0];
  const u16* axs = xb + (size_t)(m0 + srow) * K_IN + scx;
  const u16* bxs = wb + (size_t)(n0 + srow) * K_IN + scx;

  // prologue: stage tiles 0,1,2 (A,B per tile -> 6 loads)
#pragma unroll
  for (int ts = 0; ts < 3; ++ts) {
    GLOAD_LDS16(axs + ts * 32, AsF + ts * 8192 + ldst);
    GLOAD_LDS16(bxs + ts * 32, BsF + ts * 8192 + ldst);
  }
  asm volatile("s_waitcnt vmcnt(4)" ::: "memory");  // tile 0 landed (this wave)
  asm volatile("s_barrier" ::: "memory");           // => landed cross-wave

  const int abase = (wm * 64 + r15) * 32 + cxr;  // mi stride 16 rows = 512 u16
  const int bbase = (wn * 64 + r15) * 32 + cxr;

  // running stage pointers -> tile 3
  const u16* ap = axs + 96;
  const u16* bp = bxs + 96;

  bf16x8 fa[4], fb[4];  // full-tile frag set (K=32 per bf16x8), rewritten each tile

#define SA(DST) { GLOAD_LDS16(ap, AsF + (DST) * 8192 + ldst); ap += 32; }
#define SB(DST) { GLOAD_LDS16(bp, BsF + (DST) * 8192 + ldst); bp += 32; }
#define W2  asm volatile("s_waitcnt vmcnt(2)" ::: "memory");
#define W0  asm volatile("s_waitcnt vmcnt(0)" ::: "memory");
#define BARR asm volatile("s_barrier" ::: "memory");
#define READN(NS)                                                                   \
  { const u16* An = AsF + (NS) * 8192;                                              \
    const u16* Bn = BsF + (NS) * 8192;                                              \
    _Pragma("unroll") for (int mi = 0; mi < 4; ++mi)                                \
        fa[mi] = *(const bf16x8*)&An[abase + mi * 512];                             \
    _Pragma("unroll") for (int nj = 0; nj < 4; ++nj)                                \
        fb[nj] = *(const bf16x8*)&Bn[bbase + nj * 512]; }

#define TILE(STAGE, WAIT, RD, BAR)                                                  \
  {                                                                                 \
    STAGE                                                                           \
    __builtin_amdgcn_s_setprio(1);                                                  \
    _Pragma("unroll") for (int mi = 0; mi < 4; ++mi)                                \
    _Pragma("unroll") for (int nj = 0; nj < 4; ++nj)                                \
        acc[mi][nj] =                                                               \
            __builtin_amdgcn_mfma_f32_16x16x32_bf16(fa[mi], fb[nj], acc[mi][nj], 0, 0, 0); \
    __builtin_amdgcn_s_setprio(0);                                                  \
    WAIT                                                                            \
    RD                                                                              \
    BAR                                                                             \
  }

  READN(0)  // tile 0 frags (post-prologue-barrier: globally landed)

  // main loop: tiles 0..123, staging 3..127
#pragma unroll 1
  for (int t = 0; t < 124; t += 4) {
    TILE(SA(3) SB(3), W2, READN(1), BARR)
    TILE(SA(0) SB(0), W2, READN(2), BARR)
    TILE(SA(1) SB(1), W2, READN(3), BARR)
    TILE(SA(2) SB(2), W2, READN(0), BARR)
  }
  // t=124: stage tile 127 -> slot 3
  TILE(SA(3) SB(3), W2, READN(1), BARR)
  // t=125: stage LoRA tile (128) -> slot 0
  {
    const u16* la = t32 + (size_t)(m0 + srow) * RANK + scx;
    const u16* lb = a32 + (size_t)(n0 + srow) * RANK + scx;
    TILE({ GLOAD_LDS16(la, AsF + 0 * 8192 + ldst); GLOAD_LDS16(lb, BsF + 0 * 8192 + ldst); },
         W2, READN(2), BARR)
  }
  // t=126: full drain so LoRA slot is globally landed after this barrier
  TILE(, W0, READN(3), BARR)
  // t=127: nothing outstanding; pre-read LoRA frags (slot 0)
  TILE(, , READN(0), BARR)
  // t=128: LoRA tile, frags preloaded
  TILE(, , , )

  // epilogue: out = acc*scale[col] + bias[col]
#pragma unroll
  for (int nj = 0; nj < 4; ++nj) {
    int col = n0 + wn * 64 + nj * 16 + r15;
    float s = scale[col], bv = bias[col];
#pragma unroll
    for (int mi = 0; mi < 4; ++mi) {
      int row = m0 + wm * 64 + mi * 16 + (l >> 4) * 4;
#pragma unroll
      for (int r = 0; r < 4; ++r)
        out[(size_t)(row + r) * N_OUT + col] = acc[mi][nj][r] * s + bv;
    }
  }
}

// ---------- launch ----------
extern "C" void kernel_launch(void* const* d_in, const int* in_sizes, int n_in,
                              void* d_out, int out_size, void* d_ws, size_t ws_size,
                              hipStream_t stream) {
  const float* x     = (const float*)d_in[0];
  const void*  wq    = d_in[1];
  const float* scale = (const float*)d_in[2];
  const float* loraA = (const float*)d_in[3];
  const float* loraB = (const float*)d_in[4];
  const float* bias  = (const float*)d_in[5];
  float* out = (float*)d_out;

  char* ws = (char*)d_ws;
  u16*   xb    = (u16*)(ws + WS_XB);
  u16*   wbuf  = (u16*)(ws + WS_WB);
  u16*   bb    = (u16*)(ws + WS_BB);
  u16*   a32   = (u16*)(ws + WS_A32);
  u16*   t32   = (u16*)(ws + WS_T32);
  float* tpart = (float*)(ws + WS_TPART);
  int*   flag  = (int*)(ws + WS_FLAG);

  k_prep<<<1024, 256, 0, stream>>>((const int*)wq, loraA, loraB, scale, bb, a32, flag);
  k_convert_x<<<2048, 256, 0, stream>>>((const float4*)x, (ushort4*)xb, M_TOK * K_IN / 4);
  k_convert_w<<<2048, 256, 0, stream>>>(wq, flag, (ushort4*)wbuf, N_OUT * K_IN / 4);
  k_lora_T<<<256, 256, 0, stream>>>(xb, bb, tpart);
  k_reduce_T<<<1024, 256, 0, stream>>>(tpart, t32);
  k_gemm8<<<512, 1024, 0, stream>>>(xb, wbuf, t32, a32, scale, bias, out);

  (void)in_sizes; (void)n_in; (void)out_size; (void)ws_size;
}

// Round 13
// 315.531 us; speedup vs baseline: 1.6982x; 1.0147x over previous
//
#include <hip/hip_runtime.h>
#include <stdint.h>

typedef unsigned short u16;
typedef __attribute__((ext_vector_type(8))) __bf16 bf16x8;
typedef __attribute__((ext_vector_type(4))) float f32x4;

// ---------- helpers ----------
__device__ __forceinline__ u16 f2bf(float f) {  // RNE fp32 -> bf16
  unsigned int u = __builtin_bit_cast(unsigned int, f);
  u = (u + 0x7FFFu + ((u >> 16) & 1u)) >> 16;
  return (u16)u;
}
__device__ __forceinline__ u16 tern2bf(int s) {
  return s == 0 ? (u16)0 : (s > 0 ? (u16)0x3F80 : (u16)0xBF80);
}

#define GLOAD_LDS16(g, l)                                                          \
  __builtin_amdgcn_global_load_lds((__attribute__((address_space(1))) void*)(g),   \
                                   (__attribute__((address_space(3))) void*)(l),   \
                                   16, 0, 0)

// ---------- problem sizes ----------
#define M_TOK 8192
#define N_OUT 4096
#define K_IN  4096
#define RANK  32

// ---------- ws layout (bytes) ----------
#define WS_XB    0ull
#define WS_WB    67108864ull
#define WS_BB    100663296ull
#define WS_A32   100925440ull
#define WS_T32   101187584ull
#define WS_TPART 101711872ull
#define WS_FLAG  110100480ull

// ---------- prep kernels (R9-proven split set) ----------
__global__ void k_convert_x(const float4* __restrict__ x, ushort4* __restrict__ xb, int n4) {
  int stride = gridDim.x * blockDim.x;
  for (int i = blockIdx.x * blockDim.x + threadIdx.x; i < n4; i += stride) {
    float4 v = x[i];
    ushort4 o;
    o.x = f2bf(v.x); o.y = f2bf(v.y); o.z = f2bf(v.z); o.w = f2bf(v.w);
    xb[i] = o;
  }
}

__global__ void k_detect_wtype(const int* __restrict__ w, int* __restrict__ flag) {
  int v = w[threadIdx.x];
  bool ok = (v >= -1 && v <= 1);
  unsigned long long m = __ballot(ok);
  if (threadIdx.x == 0) *flag = (m == ~0ull) ? 1 : 0;
}

__global__ void k_convert_w(const void* __restrict__ wq, const int* __restrict__ flag,
                            ushort4* __restrict__ wb, int n4) {
  int is32 = *flag;
  int stride = gridDim.x * blockDim.x;
  for (int i = blockIdx.x * blockDim.x + threadIdx.x; i < n4; i += stride) {
    int s0, s1, s2, s3;
    if (is32) {
      int4 c = ((const int4*)wq)[i];
      s0 = c.x; s1 = c.y; s2 = c.z; s3 = c.w;
    } else {
      char4 c = ((const char4*)wq)[i];
      s0 = c.x; s1 = c.y; s2 = c.z; s3 = c.w;
    }
    ushort4 o;
    o.x = tern2bf(s0); o.y = tern2bf(s1); o.z = tern2bf(s2); o.w = tern2bf(s3);
    wb[i] = o;
  }
}

__global__ void k_prep_B(const float* __restrict__ loraB, u16* __restrict__ bb) {
  int idx = blockIdx.x * blockDim.x + threadIdx.x;
  if (idx < RANK * K_IN) bb[idx] = f2bf(loraB[idx]);
}

__global__ void k_prep_A(const float* __restrict__ loraA, const float* __restrict__ scale,
                         u16* __restrict__ a32) {
  int idx = blockIdx.x * blockDim.x + threadIdx.x;
  if (idx >= N_OUT * RANK) return;
  int o = idx >> 5;
  a32[idx] = f2bf(loraA[idx] / scale[o]);
}

// ---------- T = x @ B^T (MFMA; 1024 blocks = 128 M-tiles x 8 K-slices) ----------
// Block: 64 tokens x 512-k slice; 4 waves, each one 16-row MFMA tile.
// LDS 6KB -> high occupancy (was 256 blocks / 18KB, latency-bound).
__global__ __launch_bounds__(256) void k_lora_T(const u16* __restrict__ xb,
                                                const u16* __restrict__ bb,
                                                float* __restrict__ tpart) {
  __shared__ u16 As[64 * 32];  // 4 KB
  __shared__ u16 Bs[32 * 32];  // 2 KB
  int mt = blockIdx.x >> 3;    // 0..127
  int ks = blockIdx.x & 7;     // 0..7
  int tid = threadIdx.x, lane = tid & 63, wv = tid >> 6;
  int m0 = mt * 64;
  int kbase0 = ks * 512;
  f32x4 acc[2] = {};
  for (int step = 0; step < 16; ++step) {
    int kb = kbase0 + step * 32;
    __syncthreads();
    {  // As: 64 rows x 4 chunks = 256 chunks, 1/thread
      const u16* src = xb + (size_t)(m0 + (tid >> 2)) * K_IN + kb + (tid & 3) * 8;
      GLOAD_LDS16(src, &As[tid * 8]);
    }
    if (tid < 128) {  // Bs: 32 rows x 4 chunks
      const u16* src = bb + (size_t)(tid >> 2) * K_IN + kb + (tid & 3) * 8;
      GLOAD_LDS16(src, &Bs[tid * 8]);
    }
    __syncthreads();
    bf16x8 a = *(const bf16x8*)&As[(wv * 16 + (lane & 15)) * 32 + (lane >> 4) * 8];
#pragma unroll
    for (int ni = 0; ni < 2; ++ni) {
      bf16x8 b = *(const bf16x8*)&Bs[(ni * 16 + (lane & 15)) * 32 + (lane >> 4) * 8];
      acc[ni] = __builtin_amdgcn_mfma_f32_16x16x32_bf16(a, b, acc[ni], 0, 0, 0);
    }
  }
#pragma unroll
  for (int ni = 0; ni < 2; ++ni)
#pragma unroll
    for (int r = 0; r < 4; ++r) {
      int row = m0 + wv * 16 + (lane >> 4) * 4 + r;
      int col = ni * 16 + (lane & 15);
      tpart[((size_t)ks * M_TOK + row) * RANK + col] = acc[ni][r];
    }
}

__global__ void k_reduce_T(const float* __restrict__ tpart, u16* __restrict__ t32) {
  int idx = blockIdx.x * blockDim.x + threadIdx.x;
  if (idx >= M_TOK * RANK) return;
  int t = idx >> 5, r = idx & 31;
  float v = 0.f;
#pragma unroll
  for (int s = 0; s < 8; ++s) v += tpart[((size_t)s * M_TOK + t) * RANK + r];
  t32[idx] = f2bf(v);
}

// ---------- main GEMM: EXACT R12 kernel (231.5us, MfmaUtil 54%, 0 conflicts) ----------
// 256x256, BK=32, ring-4 LDS, 16 waves (4Mx4N), full-tile frag read-ahead,
// counted vmcnt, 1 barrier/tile.
__global__ __launch_bounds__(1024, 4) void k_gemm8(const u16* __restrict__ xb,
                                                   const u16* __restrict__ wb,
                                                   const u16* __restrict__ t32,
                                                   const u16* __restrict__ a32,
                                                   const float* __restrict__ scale,
                                                   const float* __restrict__ bias,
                                                   float* __restrict__ out) {
  __shared__ u16 As[4][8192];  // 4 slots x 16KB
  __shared__ u16 Bs[4][8192];
  const int tid = threadIdx.x;
  const int l = tid & 63, w = tid >> 6;     // 16 waves
  const int wm = w >> 2, wn = w & 3;        // 4M x 4N
  const int bid = blockIdx.x;
  const int swz = (bid & 7) * 64 + (bid >> 3);
  const int m0 = (swz >> 4) * 256, n0 = (swz & 15) * 256;

  const int srow = tid >> 2;                       // 0..255
  const int scx = ((tid & 3) ^ ((tid >> 3) & 3)) * 8;
  const int ldst = tid * 8;
  const int r15 = l & 15;
  const int cxr = (((l >> 4) ^ ((r15 >> 1) & 3)) * 8);

  f32x4 acc[4][4] = {};

  u16* AsF = &As[0][0];
  u16* BsF = &Bs[0][0];
  const u16* axs = xb + (size_t)(m0 + srow) * K_IN + scx;
  const u16* bxs = wb + (size_t)(n0 + srow) * K_IN + scx;

  // prologue: stage tiles 0,1,2
#pragma unroll
  for (int ts = 0; ts < 3; ++ts) {
    GLOAD_LDS16(axs + ts * 32, AsF + ts * 8192 + ldst);
    GLOAD_LDS16(bxs + ts * 32, BsF + ts * 8192 + ldst);
  }
  asm volatile("s_waitcnt vmcnt(4)" ::: "memory");
  asm volatile("s_barrier" ::: "memory");

  const int abase = (wm * 64 + r15) * 32 + cxr;
  const int bbase = (wn * 64 + r15) * 32 + cxr;

  const u16* ap = axs + 96;
  const u16* bp = bxs + 96;

  bf16x8 fa[4], fb[4];

#define SA(DST) { GLOAD_LDS16(ap, AsF + (DST) * 8192 + ldst); ap += 32; }
#define SB(DST) { GLOAD_LDS16(bp, BsF + (DST) * 8192 + ldst); bp += 32; }
#define W2  asm volatile("s_waitcnt vmcnt(2)" ::: "memory");
#define W0  asm volatile("s_waitcnt vmcnt(0)" ::: "memory");
#define BARR asm volatile("s_barrier" ::: "memory");
#define READN(NS)                                                                   \
  { const u16* An = AsF + (NS) * 8192;                                              \
    const u16* Bn = BsF + (NS) * 8192;                                              \
    _Pragma("unroll") for (int mi = 0; mi < 4; ++mi)                                \
        fa[mi] = *(const bf16x8*)&An[abase + mi * 512];                             \
    _Pragma("unroll") for (int nj = 0; nj < 4; ++nj)                                \
        fb[nj] = *(const bf16x8*)&Bn[bbase + nj * 512]; }

#define TILE(STAGE, WAIT, RD, BAR)                                                  \
  {                                                                                 \
    STAGE                                                                           \
    __builtin_amdgcn_s_setprio(1);                                                  \
    _Pragma("unroll") for (int mi = 0; mi < 4; ++mi)                                \
    _Pragma("unroll") for (int nj = 0; nj < 4; ++nj)                                \
        acc[mi][nj] =                                                               \
            __builtin_amdgcn_mfma_f32_16x16x32_bf16(fa[mi], fb[nj], acc[mi][nj], 0, 0, 0); \
    __builtin_amdgcn_s_setprio(0);                                                  \
    WAIT                                                                            \
    RD                                                                              \
    BAR                                                                             \
  }

  READN(0)

  // main loop: tiles 0..123, staging 3..127
#pragma unroll 1
  for (int t = 0; t < 124; t += 4) {
    TILE(SA(3) SB(3), W2, READN(1), BARR)
    TILE(SA(0) SB(0), W2, READN(2), BARR)
    TILE(SA(1) SB(1), W2, READN(3), BARR)
    TILE(SA(2) SB(2), W2, READN(0), BARR)
  }
  // t=124: stage tile 127 -> slot 3
  TILE(SA(3) SB(3), W2, READN(1), BARR)
  // t=125: stage LoRA tile (128) -> slot 0
  {
    const u16* la = t32 + (size_t)(m0 + srow) * RANK + scx;
    const u16* lb = a32 + (size_t)(n0 + srow) * RANK + scx;
    TILE({ GLOAD_LDS16(la, AsF + 0 * 8192 + ldst); GLOAD_LDS16(lb, BsF + 0 * 8192 + ldst); },
         W2, READN(2), BARR)
  }
  // t=126: full drain so LoRA slot is globally landed after this barrier
  TILE(, W0, READN(3), BARR)
  // t=127: pre-read LoRA frags (slot 0)
  TILE(, , READN(0), BARR)
  // t=128: LoRA tile
  TILE(, , , )

  // epilogue: out = acc*scale[col] + bias[col]
#pragma unroll
  for (int nj = 0; nj < 4; ++nj) {
    int col = n0 + wn * 64 + nj * 16 + r15;
    float s = scale[col], bv = bias[col];
#pragma unroll
    for (int mi = 0; mi < 4; ++mi) {
      int row = m0 + wm * 64 + mi * 16 + (l >> 4) * 4;
#pragma unroll
      for (int r = 0; r < 4; ++r)
        out[(size_t)(row + r) * N_OUT + col] = acc[mi][nj][r] * s + bv;
    }
  }
}

// ---------- launch ----------
extern "C" void kernel_launch(void* const* d_in, const int* in_sizes, int n_in,
                              void* d_out, int out_size, void* d_ws, size_t ws_size,
                              hipStream_t stream) {
  const float* x     = (const float*)d_in[0];
  const void*  wq    = d_in[1];
  const float* scale = (const float*)d_in[2];
  const float* loraA = (const float*)d_in[3];
  const float* loraB = (const float*)d_in[4];
  const float* bias  = (const float*)d_in[5];
  float* out = (float*)d_out;

  char* ws = (char*)d_ws;
  u16*   xb    = (u16*)(ws + WS_XB);
  u16*   wbuf  = (u16*)(ws + WS_WB);
  u16*   bb    = (u16*)(ws + WS_BB);
  u16*   a32   = (u16*)(ws + WS_A32);
  u16*   t32   = (u16*)(ws + WS_T32);
  float* tpart = (float*)(ws + WS_TPART);
  int*   flag  = (int*)(ws + WS_FLAG);

  k_convert_x<<<2048, 256, 0, stream>>>((const float4*)x, (ushort4*)xb, M_TOK * K_IN / 4);
  k_detect_wtype<<<1, 64, 0, stream>>>((const int*)wq, flag);
  k_prep_B<<<512, 256, 0, stream>>>(loraB, bb);
  k_prep_A<<<512, 256, 0, stream>>>(loraA, scale, a32);
  k_convert_w<<<2048, 256, 0, stream>>>(wq, flag, (ushort4*)wbuf, N_OUT * K_IN / 4);
  k_lora_T<<<1024, 256, 0, stream>>>(xb, bb, tpart);
  k_reduce_T<<<1024, 256, 0, stream>>>(tpart, t32);
  k_gemm8<<<512, 1024, 0, stream>>>(xb, wbuf, t32, a32, scale, bias, out);

  (void)in_sizes; (void)n_in; (void)out_size; (void)ws_size;
}

// Round 14
// 314.890 us; speedup vs baseline: 1.7016x; 1.0020x over previous
//
#include <hip/hip_runtime.h>
#include <stdint.h>

typedef unsigned short u16;
typedef __attribute__((ext_vector_type(8))) __bf16 bf16x8;
typedef __attribute__((ext_vector_type(4))) float f32x4;

// ---------- helpers ----------
__device__ __forceinline__ u16 f2bf(float f) {  // RNE fp32 -> bf16
  unsigned int u = __builtin_bit_cast(unsigned int, f);
  u = (u + 0x7FFFu + ((u >> 16) & 1u)) >> 16;
  return (u16)u;
}
__device__ __forceinline__ u16 tern2bf(int s) {
  return s == 0 ? (u16)0 : (s > 0 ? (u16)0x3F80 : (u16)0xBF80);
}

#define GLOAD_LDS16(g, l)                                                          \
  __builtin_amdgcn_global_load_lds((__attribute__((address_space(1))) void*)(g),   \
                                   (__attribute__((address_space(3))) void*)(l),   \
                                   16, 0, 0)

// ---------- problem sizes ----------
#define M_TOK 8192
#define N_OUT 4096
#define K_IN  4096
#define RANK  32

// ---------- ws layout (bytes) ----------
#define WS_XB    0ull
#define WS_WB    67108864ull
#define WS_BB    100663296ull
#define WS_A32   100925440ull
#define WS_T32   101187584ull
#define WS_TPART 101711872ull
#define WS_FLAG  110100480ull

// ---------- prep kernels ----------
__global__ void k_detect_wtype(const int* __restrict__ w, int* __restrict__ flag) {
  int v = w[threadIdx.x];
  bool ok = (v >= -1 && v <= 1);
  unsigned long long m = __ballot(ok);
  if (threadIdx.x == 0) *flag = (m == ~0ull) ? 1 : 0;
}

__global__ void k_convert_w(const void* __restrict__ wq, const int* __restrict__ flag,
                            ushort4* __restrict__ wb, int n4) {
  int is32 = *flag;
  int stride = gridDim.x * blockDim.x;
  for (int i = blockIdx.x * blockDim.x + threadIdx.x; i < n4; i += stride) {
    int s0, s1, s2, s3;
    if (is32) {
      int4 c = ((const int4*)wq)[i];
      s0 = c.x; s1 = c.y; s2 = c.z; s3 = c.w;
    } else {
      char4 c = ((const char4*)wq)[i];
      s0 = c.x; s1 = c.y; s2 = c.z; s3 = c.w;
    }
    ushort4 o;
    o.x = tern2bf(s0); o.y = tern2bf(s1); o.z = tern2bf(s2); o.w = tern2bf(s3);
    wb[i] = o;
  }
}

__global__ void k_prep_B(const float* __restrict__ loraB, u16* __restrict__ bb) {
  int idx = blockIdx.x * blockDim.x + threadIdx.x;
  if (idx < RANK * K_IN) bb[idx] = f2bf(loraB[idx]);
}

__global__ void k_prep_A(const float* __restrict__ loraA, const float* __restrict__ scale,
                         u16* __restrict__ a32) {
  int idx = blockIdx.x * blockDim.x + threadIdx.x;
  if (idx >= N_OUT * RANK) return;
  int o = idx >> 5;
  a32[idx] = f2bf(loraA[idx] / scale[o]);
}

// ---------- fused: x f32 -> xb bf16 (single pass) + T-partials via MFMA ----------
// 1024 blocks = 128 M-tiles(64 tok) x 8 K-slices(512). Per K32-step:
// each thread loads 8 f32 of x (row tid>>2, cols (tid&3)*8), converts,
// stores packed bf16 to xb (once, exact coverage), ds_writes the same 16B
// into As[64][32]; Bs[32][32] staged from bb via gload_lds. Then the same
// MFMA as the proven k_lora_T. Row stride 64B in both tiles -> 2-way bank
// aliasing only (free). BW-bound: 192MB + B re-reads ~ 33-40us.
__global__ __launch_bounds__(256) void k_xt(const float* __restrict__ x,
                                            const u16* __restrict__ bb,
                                            uint4* __restrict__ xb,
                                            float* __restrict__ tpart) {
  __shared__ u16 As[64 * 32];  // 4 KB
  __shared__ u16 Bs[32 * 32];  // 2 KB
  int mt = blockIdx.x >> 3;    // 0..127
  int ks = blockIdx.x & 7;     // 0..7
  int tid = threadIdx.x, lane = tid & 63, wv = tid >> 6;
  int m0 = mt * 64;
  int kbase0 = ks * 512;
  const int row = tid >> 2;        // 0..63
  const int c8 = (tid & 3) * 8;    // col offset within 32
  f32x4 acc[2] = {};
  for (int step = 0; step < 16; ++step) {
    int kb = kbase0 + step * 32;
    __syncthreads();
    // x: load f32, convert, store xb, ds_write As
    {
      const float* xp = x + (size_t)(m0 + row) * K_IN + kb + c8;
      float4 v0 = *(const float4*)xp;
      float4 v1 = *(const float4*)(xp + 4);
      u16 o[8];
      o[0] = f2bf(v0.x); o[1] = f2bf(v0.y); o[2] = f2bf(v0.z); o[3] = f2bf(v0.w);
      o[4] = f2bf(v1.x); o[5] = f2bf(v1.y); o[6] = f2bf(v1.z); o[7] = f2bf(v1.w);
      uint4 pk;
      pk.x = (unsigned)o[0] | ((unsigned)o[1] << 16);
      pk.y = (unsigned)o[2] | ((unsigned)o[3] << 16);
      pk.z = (unsigned)o[4] | ((unsigned)o[5] << 16);
      pk.w = (unsigned)o[6] | ((unsigned)o[7] << 16);
      xb[((size_t)(m0 + row) * K_IN + kb + c8) / 8] = pk;
      *(uint4*)&As[tid * 8] = pk;  // As[row][c8..c8+8] since tid*8 = row*32+c8
    }
    if (tid < 128) {  // Bs: 32 rows x 4 chunks
      const u16* src = bb + (size_t)(tid >> 2) * K_IN + kb + (tid & 3) * 8;
      GLOAD_LDS16(src, &Bs[tid * 8]);
    }
    __syncthreads();
    bf16x8 a = *(const bf16x8*)&As[(wv * 16 + (lane & 15)) * 32 + (lane >> 4) * 8];
#pragma unroll
    for (int ni = 0; ni < 2; ++ni) {
      bf16x8 b = *(const bf16x8*)&Bs[(ni * 16 + (lane & 15)) * 32 + (lane >> 4) * 8];
      acc[ni] = __builtin_amdgcn_mfma_f32_16x16x32_bf16(a, b, acc[ni], 0, 0, 0);
    }
  }
#pragma unroll
  for (int ni = 0; ni < 2; ++ni)
#pragma unroll
    for (int r = 0; r < 4; ++r) {
      int orow = m0 + wv * 16 + (lane >> 4) * 4 + r;
      int col = ni * 16 + (lane & 15);
      tpart[((size_t)ks * M_TOK + orow) * RANK + col] = acc[ni][r];
    }
}

__global__ void k_reduce_T(const float* __restrict__ tpart, u16* __restrict__ t32) {
  int idx = blockIdx.x * blockDim.x + threadIdx.x;
  if (idx >= M_TOK * RANK) return;
  int t = idx >> 5, r = idx & 31;
  float v = 0.f;
#pragma unroll
  for (int s = 0; s < 8; ++s) v += tpart[((size_t)s * M_TOK + t) * RANK + r];
  t32[idx] = f2bf(v);
}

// ---------- main GEMM: EXACT R12/R13 kernel (232us, MfmaUtil 54%, 0 conflicts) ----------
__global__ __launch_bounds__(1024, 4) void k_gemm8(const u16* __restrict__ xb,
                                                   const u16* __restrict__ wb,
                                                   const u16* __restrict__ t32,
                                                   const u16* __restrict__ a32,
                                                   const float* __restrict__ scale,
                                                   const float* __restrict__ bias,
                                                   float* __restrict__ out) {
  __shared__ u16 As[4][8192];  // 4 slots x 16KB
  __shared__ u16 Bs[4][8192];
  const int tid = threadIdx.x;
  const int l = tid & 63, w = tid >> 6;     // 16 waves
  const int wm = w >> 2, wn = w & 3;        // 4M x 4N
  const int bid = blockIdx.x;
  const int swz = (bid & 7) * 64 + (bid >> 3);
  const int m0 = (swz >> 4) * 256, n0 = (swz & 15) * 256;

  const int srow = tid >> 2;                       // 0..255
  const int scx = ((tid & 3) ^ ((tid >> 3) & 3)) * 8;
  const int ldst = tid * 8;
  const int r15 = l & 15;
  const int cxr = (((l >> 4) ^ ((r15 >> 1) & 3)) * 8);

  f32x4 acc[4][4] = {};

  u16* AsF = &As[0][0];
  u16* BsF = &Bs[0][0];
  const u16* axs = xb + (size_t)(m0 + srow) * K_IN + scx;
  const u16* bxs = wb + (size_t)(n0 + srow) * K_IN + scx;

  // prologue: stage tiles 0,1,2
#pragma unroll
  for (int ts = 0; ts < 3; ++ts) {
    GLOAD_LDS16(axs + ts * 32, AsF + ts * 8192 + ldst);
    GLOAD_LDS16(bxs + ts * 32, BsF + ts * 8192 + ldst);
  }
  asm volatile("s_waitcnt vmcnt(4)" ::: "memory");
  asm volatile("s_barrier" ::: "memory");

  const int abase = (wm * 64 + r15) * 32 + cxr;
  const int bbase = (wn * 64 + r15) * 32 + cxr;

  const u16* ap = axs + 96;
  const u16* bp = bxs + 96;

  bf16x8 fa[4], fb[4];

#define SA(DST) { GLOAD_LDS16(ap, AsF + (DST) * 8192 + ldst); ap += 32; }
#define SB(DST) { GLOAD_LDS16(bp, BsF + (DST) * 8192 + ldst); bp += 32; }
#define W2  asm volatile("s_waitcnt vmcnt(2)" ::: "memory");
#define W0  asm volatile("s_waitcnt vmcnt(0)" ::: "memory");
#define BARR asm volatile("s_barrier" ::: "memory");
#define READN(NS)                                                                   \
  { const u16* An = AsF + (NS) * 8192;                                              \
    const u16* Bn = BsF + (NS) * 8192;                                              \
    _Pragma("unroll") for (int mi = 0; mi < 4; ++mi)                                \
        fa[mi] = *(const bf16x8*)&An[abase + mi * 512];                             \
    _Pragma("unroll") for (int nj = 0; nj < 4; ++nj)                                \
        fb[nj] = *(const bf16x8*)&Bn[bbase + nj * 512]; }

#define TILE(STAGE, WAIT, RD, BAR)                                                  \
  {                                                                                 \
    STAGE                                                                           \
    __builtin_amdgcn_s_setprio(1);                                                  \
    _Pragma("unroll") for (int mi = 0; mi < 4; ++mi)                                \
    _Pragma("unroll") for (int nj = 0; nj < 4; ++nj)                                \
        acc[mi][nj] =                                                               \
            __builtin_amdgcn_mfma_f32_16x16x32_bf16(fa[mi], fb[nj], acc[mi][nj], 0, 0, 0); \
    __builtin_amdgcn_s_setprio(0);                                                  \
    WAIT                                                                            \
    RD                                                                              \
    BAR                                                                             \
  }

  READN(0)

  // main loop: tiles 0..123, staging 3..127
#pragma unroll 1
  for (int t = 0; t < 124; t += 4) {
    TILE(SA(3) SB(3), W2, READN(1), BARR)
    TILE(SA(0) SB(0), W2, READN(2), BARR)
    TILE(SA(1) SB(1), W2, READN(3), BARR)
    TILE(SA(2) SB(2), W2, READN(0), BARR)
  }
  // t=124: stage tile 127 -> slot 3
  TILE(SA(3) SB(3), W2, READN(1), BARR)
  // t=125: stage LoRA tile (128) -> slot 0
  {
    const u16* la = t32 + (size_t)(m0 + srow) * RANK + scx;
    const u16* lb = a32 + (size_t)(n0 + srow) * RANK + scx;
    TILE({ GLOAD_LDS16(la, AsF + 0 * 8192 + ldst); GLOAD_LDS16(lb, BsF + 0 * 8192 + ldst); },
         W2, READN(2), BARR)
  }
  // t=126: full drain so LoRA slot is globally landed after this barrier
  TILE(, W0, READN(3), BARR)
  // t=127: pre-read LoRA frags (slot 0)
  TILE(, , READN(0), BARR)
  // t=128: LoRA tile
  TILE(, , , )

  // epilogue: out = acc*scale[col] + bias[col]
#pragma unroll
  for (int nj = 0; nj < 4; ++nj) {
    int col = n0 + wn * 64 + nj * 16 + r15;
    float s = scale[col], bv = bias[col];
#pragma unroll
    for (int mi = 0; mi < 4; ++mi) {
      int row = m0 + wm * 64 + mi * 16 + (l >> 4) * 4;
#pragma unroll
      for (int r = 0; r < 4; ++r)
        out[(size_t)(row + r) * N_OUT + col] = acc[mi][nj][r] * s + bv;
    }
  }
}

// ---------- launch ----------
extern "C" void kernel_launch(void* const* d_in, const int* in_sizes, int n_in,
                              void* d_out, int out_size, void* d_ws, size_t ws_size,
                              hipStream_t stream) {
  const float* x     = (const float*)d_in[0];
  const void*  wq    = d_in[1];
  const float* scale = (const float*)d_in[2];
  const float* loraA = (const float*)d_in[3];
  const float* loraB = (const float*)d_in[4];
  const float* bias  = (const float*)d_in[5];
  float* out = (float*)d_out;

  char* ws = (char*)d_ws;
  u16*   xb    = (u16*)(ws + WS_XB);
  u16*   wbuf  = (u16*)(ws + WS_WB);
  u16*   bb    = (u16*)(ws + WS_BB);
  u16*   a32   = (u16*)(ws + WS_A32);
  u16*   t32   = (u16*)(ws + WS_T32);
  float* tpart = (float*)(ws + WS_TPART);
  int*   flag  = (int*)(ws + WS_FLAG);

  k_detect_wtype<<<1, 64, 0, stream>>>((const int*)wq, flag);
  k_prep_B<<<512, 256, 0, stream>>>(loraB, bb);
  k_prep_A<<<512, 256, 0, stream>>>(loraA, scale, a32);
  k_convert_w<<<2048, 256, 0, stream>>>(wq, flag, (ushort4*)wbuf, N_OUT * K_IN / 4);
  k_xt<<<1024, 256, 0, stream>>>(x, bb, (uint4*)xb, tpart);
  k_reduce_T<<<1024, 256, 0, stream>>>(tpart, t32);
  k_gemm8<<<512, 1024, 0, stream>>>(xb, wbuf, t32, a32, scale, bias, out);

  (void)in_sizes; (void)n_in; (void)out_size; (void)ws_size;
}